// Round 3
// baseline (1475.894 us; speedup 1.0000x reference)
//
#include <hip/hip_runtime.h>

typedef unsigned int  u32;
typedef unsigned short u16;

#define B_SESS 4096
#define NPS    40          // nodes / session
#define SPS    50          // seq tokens / session
#define EPS    60          // edges / session
#define DIM    512
#define HID    64
#define NNODES (B_SESS * NPS)

// ---------- bf16 helpers (RNE) ----------
__device__ __forceinline__ float bf2f(u32 b) { return __uint_as_float(b << 16); }
__device__ __forceinline__ u16  f2bf(float f) {
    u32 u = __float_as_uint(f);
    return (u16)((u + 0x7fffu + ((u >> 16) & 1u)) >> 16);
}
__device__ __forceinline__ u32 pack2(float a, float b) {
    return (u32)f2bf(a) | ((u32)f2bf(b) << 16);
}

typedef __bf16 bf16x8 __attribute__((ext_vector_type(8)));
typedef float  f32x4  __attribute__((ext_vector_type(4)));

typedef const __attribute__((address_space(1))) u32 gu32;
typedef       __attribute__((address_space(3))) u32 lu32;
#define GLOAD_LDS16(gp, lp) \
    __builtin_amdgcn_global_load_lds((gu32*)(gp), (lu32*)(lp), 16, 0, 0)

// ---------- transpose + fp32->bf16 convert: dst[c*R + r] = bf16(src[r*C + c]) ----
extern "C" __global__ void k_convT(const float* __restrict__ src,
                                   u16* __restrict__ dst, int R, int C) {
    int i = blockIdx.x * 256 + threadIdx.x;
    if (i < R * C) {
        int r = i / C, c = i % C;
        dst[c * R + r] = f2bf(src[i]);
    }
}

// ---------- SGConv 2-hop propagation: fp32 hidden -> bf16 xpr ----------
// one block per (session, 256-col chunk)
extern "C" __global__ __launch_bounds__(128)
void k_prop(const float* __restrict__ hid, const int* __restrict__ eidx, int Etot,
            u16* __restrict__ xpr) {
    __shared__ float xl[NPS * 256];          // hop1 result (fp32, 40 KB)
    __shared__ int   esrc[NPS + EPS];        // CSR entry source node
    __shared__ float enrm[NPS + EPS];        // CSR entry norm
    __shared__ int   degc[NPS];
    __shared__ int   offs[NPS + 1];
    __shared__ int   cur[NPS];
    __shared__ float dinv[NPS];
    __shared__ int   se[EPS], de[EPS];

    int tid = threadIdx.x;
    int b   = blockIdx.x >> 1;
    int c0  = (blockIdx.x & 1) * 256;
    size_t nb = (size_t)b * NPS;

    if (tid < EPS) {
        se[tid] = eidx[b * EPS + tid] - (int)nb;
        de[tid] = eidx[Etot + b * EPS + tid] - (int)nb;
    }
    if (tid < NPS) degc[tid] = 1;            // self loop
    __syncthreads();
    if (tid < EPS) atomicAdd(&degc[de[tid]], 1);
    __syncthreads();
    if (tid == 0) {
        int s = 0;
        for (int i = 0; i < NPS; i++) { offs[i] = s; s += degc[i]; }
        offs[NPS] = s;                       // == NPS + EPS
    }
    if (tid < NPS) dinv[tid] = rsqrtf((float)degc[tid]);
    __syncthreads();
    if (tid < NPS) cur[tid] = offs[tid];
    __syncthreads();
    if (tid < NPS) {                         // self-loop entries
        int p = atomicAdd(&cur[tid], 1);
        esrc[p] = tid;
        enrm[p] = dinv[tid] * dinv[tid];
    }
    if (tid < EPS) {                         // real edges
        int s = se[tid], d = de[tid];
        int p = atomicAdd(&cur[d], 1);
        esrc[p] = s;
        enrm[p] = dinv[s] * dinv[d];
    }
    __syncthreads();

    // ---- hop 1: gather fp32 from global, accumulate, store fp32 to LDS ----
    for (int d = 0; d < NPS; d++) {
        float a0 = 0.f, a1 = 0.f;
        for (int p = offs[d]; p < offs[d + 1]; p++) {
            int s = esrc[p]; float nm = enrm[p];
            float2 v = *(const float2*)&hid[(nb + s) * DIM + c0 + 2 * tid];
            a0 += nm * v.x;
            a1 += nm * v.y;
        }
        xl[d * 256 + 2 * tid]     = a0;
        xl[d * 256 + 2 * tid + 1] = a1;
    }
    __syncthreads();

    // ---- hop 2: gather from LDS, write bf16 xpr ----
    for (int d = 0; d < NPS; d++) {
        float a0 = 0.f, a1 = 0.f;
        for (int p = offs[d]; p < offs[d + 1]; p++) {
            int s = esrc[p]; float nm = enrm[p];
            a0 += nm * xl[s * 256 + 2 * tid];
            a1 += nm * xl[s * 256 + 2 * tid + 1];
        }
        *(u32*)&xpr[(nb + d) * DIM + c0 + 2 * tid] = pack2(a0, a1);
    }
}

// ---------- GEMM1: C[N,512] = A[N,512] @ Wg + bg (A,BT,C bf16; bias fp32) --------
extern "C" __global__ __launch_bounds__(256)
void k_gemm(const u16* __restrict__ A, const u16* __restrict__ BT,
            const float* __restrict__ bias, u16* __restrict__ C) {
    __shared__ __align__(16) u16 As[128 * 32];
    __shared__ __align__(16) u16 Bs[128 * 32];
    int tid  = threadIdx.x, lane = tid & 63, w = tid >> 6;
    int m0   = blockIdx.x * 128, n0 = blockIdx.y * 128;
    int wm   = (w >> 1) * 64,    wn = (w & 1) * 64;
    int fr   = lane & 15,        kq = (lane >> 4) * 8;
    int lr   = lane >> 2;              // staging: row within 16-row chunk
    int lk   = (lane & 3) * 8;         // staging: k offset (u16 units)
    f32x4 acc[4][4] = {};

    for (int kt = 0; kt < 16; kt++) {
        __syncthreads();
        int k0 = kt * 32;
#pragma unroll
        for (int q = 0; q < 2; q++) {
            int r0 = (w * 2 + q) * 16;
            GLOAD_LDS16(A  + (size_t)(m0 + r0 + lr) * DIM + k0 + lk, As + r0 * 32);
            GLOAD_LDS16(BT + (size_t)(n0 + r0 + lr) * DIM + k0 + lk, Bs + r0 * 32);
        }
        __syncthreads();
        bf16x8 av[4], bv[4];
#pragma unroll
        for (int f = 0; f < 4; f++)
            av[f] = *(const bf16x8*)&As[(wm + f * 16 + fr) * 32 + kq];
#pragma unroll
        for (int f = 0; f < 4; f++)
            bv[f] = *(const bf16x8*)&Bs[(wn + f * 16 + fr) * 32 + kq];
#pragma unroll
        for (int fm = 0; fm < 4; fm++)
#pragma unroll
            for (int fn = 0; fn < 4; fn++)
                acc[fm][fn] = __builtin_amdgcn_mfma_f32_16x16x32_bf16(
                    av[fm], bv[fn], acc[fm][fn], 0, 0, 0);
    }

    float bs[4];
#pragma unroll
    for (int fn = 0; fn < 4; fn++) bs[fn] = bias[n0 + wn + fn * 16 + fr];
#pragma unroll
    for (int fm = 0; fm < 4; fm++) {
        int mb = m0 + wm + fm * 16 + (lane >> 4) * 4;
#pragma unroll
        for (int fn = 0; fn < 4; fn++) {
            int col = n0 + wn + fn * 16 + fr;
#pragma unroll
            for (int r = 0; r < 4; r++)
                C[(size_t)(mb + r) * DIM + col] = f2bf(acc[fm][fn][r] + bs[fn]);
        }
    }
}

// ---------- fused attention pooling, one block per session ----------
extern "C" __global__ __launch_bounds__(256)
void k_attn(const u16* __restrict__ xg, const float* __restrict__ W1,
            const float* __restrict__ b1, const float* __restrict__ b2,
            const u16* __restrict__ W2T, const float* __restrict__ Wq,
            const float* __restrict__ bq, const float* __restrict__ W3,
            const float* __restrict__ b3, const int* __restrict__ sidx,
            float* __restrict__ out) {
    __shared__ __align__(16) u16 th[64 * 520];   // tokens x D bf16, stride 520
    __shared__ float q1s[64], wqs[64], alphas[64], sgs[512], part[256];
    int tid = threadIdx.x, lane = tid & 63, w = tid >> 6;
    int b = blockIdx.x, sb = b * SPS;
    size_t nb = (size_t)b * NPS;

    // gather token rows (1 KB each == one global_load_lds_dwordx4 per wave)
    for (int t = w; t < SPS; t += 4) {
        size_t g = nb + sidx[sb + t];
        GLOAD_LDS16(xg + g * DIM + lane * 8, th + t * 520);
    }
    // zero pad rows 50..63 (MFMA reads them)
    for (int i = tid; i < 14 * 260; i += 256) {
        int r = i / 260, c = i % 260;
        *(u32*)&th[(50 + r) * 520 + c * 2] = 0;
    }
    if (tid < 64) wqs[tid] = Wq[tid];
    __syncthreads();

    // q1[j] = v_n @ W1 + b1 + b2   (v_n = th[49]); wave w covers a 128-k chunk
    {
        float s = 0.f;
        for (int k = 128 * w; k < 128 * w + 128; k++)
            s += bf2f(th[49 * 520 + k]) * W1[k * HID + lane];
        part[w * 64 + lane] = s;
    }
    __syncthreads();
    if (tid < 64)
        q1s[tid] = part[tid] + part[64 + tid] + part[128 + tid] + part[192 + tid]
                 + b1[tid] + b2[tid];
    __syncthreads();

    // a2 = tok_h @ W2 via MFMA; wave w owns tokens 16w..16w+15
    int fr = lane & 15, kq = (lane >> 4) * 8;
    f32x4 acc[4] = {};
    for (int kt = 0; kt < 16; kt++) {
        bf16x8 av = *(const bf16x8*)&th[(w * 16 + fr) * 520 + kt * 32 + kq];
#pragma unroll
        for (int fn = 0; fn < 4; fn++) {
            bf16x8 bv = *(const bf16x8*)&W2T[(size_t)(fn * 16 + fr) * DIM + kt * 32 + kq];
            acc[fn] = __builtin_amdgcn_mfma_f32_16x16x32_bf16(av, bv, acc[fn], 0, 0, 0);
        }
    }
    // alpha[t] = sigmoid(a2 + q1) . wq + bq  (reduce across 16-lane groups)
    float bqf = bq[0];
#pragma unroll
    for (int r = 0; r < 4; r++) {
        float s = 0.f;
#pragma unroll
        for (int fn = 0; fn < 4; fn++) {
            int j = fn * 16 + fr;
            float x = acc[fn][r] + q1s[j];
            float sg = 1.0f / (1.0f + __expf(-x));
            s += sg * wqs[j];
        }
        s += __shfl_xor(s, 1); s += __shfl_xor(s, 2);
        s += __shfl_xor(s, 4); s += __shfl_xor(s, 8);
        if (fr == 0) alphas[w * 16 + (lane >> 4) * 4 + r] = s + bqf;
    }
    __syncthreads();

    // s_g[d] = sum_t alpha[t] * tok_h[t][d]
    {
        float a0 = 0.f, a1 = 0.f;
        int d = tid * 2;
        for (int t = 0; t < SPS; t++) {
            float al = alphas[t];
            u32 xv = *(const u32*)&th[t * 520 + d];
            a0 += al * bf2f(xv & 0xffffu);
            a1 += al * bf2f(xv >> 16);
        }
        sgs[d] = a0; sgs[d + 1] = a1;
    }
    __syncthreads();

    // h_s = [v_n, s_g] @ W3 + b3   (W3 fp32)
    {
        float s = 0.f;
        for (int k = 256 * w; k < 256 * w + 256; k++) {
            float v = (k < DIM) ? bf2f(th[49 * 520 + k]) : sgs[k - DIM];
            s += v * W3[k * HID + lane];
        }
        part[w * 64 + lane] = s;
    }
    __syncthreads();
    if (tid < 64) {
        out[b * HID + tid] = part[tid] + part[64 + tid] + part[128 + tid]
                           + part[192 + tid] + b3[tid];
    }
}

extern "C" void kernel_launch(void* const* d_in, const int* in_sizes, int n_in,
                              void* d_out, int out_size, void* d_ws, size_t ws_size,
                              hipStream_t stream) {
    const float* hidden = (const float*)d_in[0];
    const float* Wg     = (const float*)d_in[1];
    const float* bg     = (const float*)d_in[2];
    const float* W1     = (const float*)d_in[3];
    const float* b1     = (const float*)d_in[4];
    const float* W2     = (const float*)d_in[5];
    const float* b2     = (const float*)d_in[6];
    const float* Wq     = (const float*)d_in[7];
    const float* bq     = (const float*)d_in[8];
    const float* W3     = (const float*)d_in[9];
    const float* b3     = (const float*)d_in[10];
    const int*   eidx   = (const int*)d_in[11];
    const int*   sidx   = (const int*)d_in[13];
    int Etot = in_sizes[11] / 2;

    char* ws = (char*)d_ws;
    u16* xpr = (u16*)ws;                                   // N*D bf16 (160 MB)
    u16* xg  = (u16*)(ws + (size_t)NNODES * DIM * 2);      // N*D bf16 (160 MB)
    u16* WgT = (u16*)(ws + (size_t)NNODES * DIM * 4);      // 512x512 bf16
    u16* W2T = WgT + DIM * DIM;                            // 64x512  bf16

    k_convT<<<dim3((DIM * DIM + 255) / 256), 256, 0, stream>>>(Wg, WgT, DIM, DIM);
    k_convT<<<dim3((DIM * HID + 255) / 256), 256, 0, stream>>>(W2, W2T, DIM, HID);
    k_prop<<<dim3(B_SESS * 2), 128, 0, stream>>>(hidden, eidx, Etot, xpr);
    k_gemm<<<dim3(NNODES / 128, DIM / 128), 256, 0, stream>>>(xpr, WgT, bg, xg);
    k_attn<<<dim3(B_SESS), 256, 0, stream>>>(xg, W1, b1, b2, W2T, Wq, bq, W3, b3,
                                             sidx, (float*)d_out);
}